// Round 1
// 491.437 us; speedup vs baseline: 1.0386x; 1.0386x over previous
//
#include <hip/hip_runtime.h>
#include <math.h>

#define BT_TOTAL 65536
#define DIN 512
#define DEMB 256
#define KCODES 1024

typedef __attribute__((ext_vector_type(8))) short short8;
typedef __attribute__((ext_vector_type(4))) float floatx4;
typedef __attribute__((ext_vector_type(16))) float floatx16;

__device__ __forceinline__ unsigned short f2bf(float x) {
    unsigned u = __float_as_uint(x);
    unsigned r = u + 0x7fffu + ((u >> 16) & 1u);
    return (unsigned short)(r >> 16);
}
__device__ __forceinline__ float bf2f(unsigned short h) {
    return __uint_as_float(((unsigned)h) << 16);
}

// ---------------- K0a: codebook row norms + zero loss outputs ---------------
__global__ __launch_bounds__(256) void cnorm_kernel(const float* __restrict__ cbook,
                                                    float* __restrict__ cnorm,
                                                    float* __restrict__ out_loss) {
    const int k = blockIdx.x;
    const int tid = threadIdx.x;
    float v = cbook[k * DEMB + tid];
    v *= v;
#pragma unroll
    for (int o = 32; o > 0; o >>= 1) v += __shfl_down(v, o);
    __shared__ float ps[4];
    if ((tid & 63) == 0) ps[tid >> 6] = v;
    __syncthreads();
    if (tid == 0) cnorm[k] = ps[0] + ps[1] + ps[2] + ps[3];
    if (k == 0 && tid < 32) out_loss[tid] = 0.0f;
}

// ---------------- K0b: split+swizzle [N][K] row-major into 16x16x32 MFMA
// B-frag order (used by gemm_down): offset(c,k) = (((c>>4)*(K/32)+(k>>5))*64+lane)*8+(k&7),
// lane = ((k>>3)&3)*16 + (c&15).
__global__ __launch_bounds__(256) void swz_kernel(const float* __restrict__ Bt,
                                                  unsigned short* __restrict__ hi,
                                                  unsigned short* __restrict__ lo,
                                                  int K, int total) {
    const int o = blockIdx.x * 256 + threadIdx.x;
    if (o >= total) return;
    const int j = o & 7;
    const int l = (o >> 3) & 63;
    const int r = o >> 9;
    const int kst = K >> 5;
    const int s = r % kst;
    const int t = r / kst;
    const int c = t * 16 + (l & 15);
    const int k = s * 32 + (l >> 4) * 8 + j;
    const float v = Bt[(size_t)c * K + k];
    const unsigned short h = f2bf(v);
    hi[o] = (unsigned short)h;
    lo[o] = f2bf(v - bf2f(h));
}

// ---------------- K0c: split+swizzle [N][K] row-major into 32x32x16 MFMA
// B-frag order (used by dist): for code c, depth k:
//   t = c>>5 (32-code tile), s = k>>4 (16-deep chunk),
//   lane = ((k>>3)&1)*32 + (c&31), j = k&7
//   offset = ((t*(K/16) + s)*64 + lane)*8 + j
__global__ __launch_bounds__(256) void swz32_kernel(const float* __restrict__ Bt,
                                                    unsigned short* __restrict__ hi,
                                                    unsigned short* __restrict__ lo,
                                                    int K, int total) {
    const int o = blockIdx.x * 256 + threadIdx.x;
    if (o >= total) return;
    const int j = o & 7;
    const int l = (o >> 3) & 63;
    const int r = o >> 9;
    const int kst = K >> 4;
    const int s = r % kst;
    const int t = r / kst;
    const int c = t * 32 + (l & 31);
    const int k = s * 16 + (l >> 5) * 8 + j;
    const float v = Bt[(size_t)c * K + k];
    const unsigned short h = f2bf(v);
    hi[o] = (unsigned short)h;
    lo[o] = f2bf(v - bf2f(h));
}

// ---------------- fp32 VALU GEMM (for tiny P-matrix): C = A * Bt^T ----------
template <int KD, int NSTR>
__global__ __launch_bounds__(256) void gemm_rowdot(const float* __restrict__ A,
                                                   const float* __restrict__ Bt,
                                                   float* __restrict__ C) {
    __shared__ __align__(16) float As[64][36];
    __shared__ __align__(16) float Bs[64][36];
    const int tid = threadIdx.x;
    const int tx = tid & 15, ty = tid >> 4;
    const int rowBase = blockIdx.x * 64;
    const int colBase = blockIdx.y * 64;
    const int lr = tid >> 2;
    const int lk = (tid & 3) * 8;
    float acc[4][4] = {};
    for (int k0 = 0; k0 < KD; k0 += 32) {
        const float4 a0 = *(const float4*)(A + (size_t)(rowBase + lr) * KD + k0 + lk);
        const float4 a1 = *(const float4*)(A + (size_t)(rowBase + lr) * KD + k0 + lk + 4);
        const float4 b0 = *(const float4*)(Bt + (size_t)(colBase + lr) * KD + k0 + lk);
        const float4 b1 = *(const float4*)(Bt + (size_t)(colBase + lr) * KD + k0 + lk + 4);
        __syncthreads();
        *(float4*)&As[lr][lk] = a0;
        *(float4*)&As[lr][lk + 4] = a1;
        *(float4*)&Bs[lr][lk] = b0;
        *(float4*)&Bs[lr][lk + 4] = b1;
        __syncthreads();
#pragma unroll
        for (int e = 0; e < 32; e += 4) {
            float4 va[4], vb[4];
#pragma unroll
            for (int i = 0; i < 4; ++i) va[i] = *(const float4*)&As[4 * ty + i][e];
#pragma unroll
            for (int j = 0; j < 4; ++j) vb[j] = *(const float4*)&Bs[4 * tx + j][e];
#pragma unroll
            for (int i = 0; i < 4; ++i)
#pragma unroll
                for (int j = 0; j < 4; ++j) {
                    acc[i][j] = fmaf(va[i].x, vb[j].x, acc[i][j]);
                    acc[i][j] = fmaf(va[i].y, vb[j].y, acc[i][j]);
                    acc[i][j] = fmaf(va[i].z, vb[j].z, acc[i][j]);
                    acc[i][j] = fmaf(va[i].w, vb[j].w, acc[i][j]);
                }
        }
    }
#pragma unroll
    for (int i = 0; i < 4; ++i) {
        float4 o = make_float4(acc[i][0], acc[i][1], acc[i][2], acc[i][3]);
        *(float4*)(C + (size_t)(rowBase + 4 * ty + i) * NSTR + colBase + 4 * tx) = o;
    }
}

// ---------------- K1: z_e_down = z_e @ W_down^T  (MFMA bf16x2, LDS-staged B)
__global__ __launch_bounds__(256) void gemm_down_mfma(const float* __restrict__ A,
                                                      const unsigned short* __restrict__ bhi,
                                                      const unsigned short* __restrict__ blo,
                                                      float* __restrict__ C) {
    __shared__ __align__(16) short lds_h[16][512];  // [t][lane*8] for current s
    __shared__ __align__(16) short lds_l[16][512];
    const int tid = threadIdx.x;
    const int lane = tid & 63, wv = tid >> 6;
    const int m = lane & 15, q = lane >> 4;
    const int rowBase = blockIdx.x * 64 + wv * 16;

    floatx4 acc[16];
#pragma unroll
    for (int t = 0; t < 16; ++t) acc[t] = (floatx4){0.f, 0.f, 0.f, 0.f};

    for (int s = 0; s < 16; ++s) {  // K = 512, chunks of 32
        // A chunk for this wave's rows (global, overlaps barrier wait)
        const float4* ap = (const float4*)(A + (size_t)(rowBase + m) * DIN + s * 32 + q * 8);
        const float4 v0 = ap[0], v1 = ap[1];
        __syncthreads();  // previous-iteration LDS reads done
        // stage B fragments for this s: 32 chunks of 1 KB over 4 waves
#pragma unroll
        for (int i = 0; i < 8; ++i) {
            const int c = wv * 8 + i;
            const int t = c >> 1;
            const unsigned short* src = (c & 1) ? blo : bhi;
            const short8 vst = *(const short8*)(src + ((size_t)(t * 16 + s) * 64 + lane) * 8);
            short* dst = (c & 1) ? &lds_l[t][lane * 8] : &lds_h[t][lane * 8];
            *(short8*)dst = vst;
        }
        // convert A to hi/lo fragments
        const float xs[8] = {v0.x, v0.y, v0.z, v0.w, v1.x, v1.y, v1.z, v1.w};
        short8 ahi, alo;
#pragma unroll
        for (int j = 0; j < 8; ++j) {
            const unsigned short h = f2bf(xs[j]);
            ahi[j] = (short)h;
            alo[j] = (short)f2bf(xs[j] - bf2f(h));
        }
        __syncthreads();
#pragma unroll
        for (int t = 0; t < 16; ++t) {
            const short8 bh = *(const short8*)&lds_h[t][lane * 8];
            const short8 bl = *(const short8*)&lds_l[t][lane * 8];
            acc[t] = __builtin_amdgcn_mfma_f32_16x16x32_bf16(ahi, bh, acc[t], 0, 0, 0);
            acc[t] = __builtin_amdgcn_mfma_f32_16x16x32_bf16(alo, bh, acc[t], 0, 0, 0);
            acc[t] = __builtin_amdgcn_mfma_f32_16x16x32_bf16(ahi, bl, acc[t], 0, 0, 0);
        }
    }
#pragma unroll
    for (int t = 0; t < 16; ++t)
#pragma unroll
        for (int r = 0; r < 4; ++r)
            C[(size_t)(rowBase + q * 4 + r) * DEMB + t * 16 + m] = acc[t][r];
}

// ---------------- K2: dist + argmin + losses -------------------------------
// v2: 32x32x16 MFMA, 32 rows/wave (A hi/lo resident in regs, full K=256),
// 128 rows/block, grid=512 (2 blocks/CU, all co-resident).
// t-loop: 32 code-tiles of 32 codes, each split into 2 K-phases of 8 chunks.
// T14 async-STAGE: global->reg before MFMA cluster, reg->LDS after.
#define DIST_CHUNKS(BASE)                                                                     \
    {                                                                                         \
        _Pragma("unroll") for (int s8 = 0; s8 < 8; s8 += 2) {                                 \
            const short8 bh0 = *(const short8*)&lds_h[buf][s8][lane * 8];                     \
            const short8 bl0 = *(const short8*)&lds_l[buf][s8][lane * 8];                     \
            const short8 bh1 = *(const short8*)&lds_h[buf][s8 + 1][lane * 8];                 \
            const short8 bl1 = *(const short8*)&lds_l[buf][s8 + 1][lane * 8];                 \
            accA = __builtin_amdgcn_mfma_f32_32x32x16_bf16(ahi[BASE + s8], bh0, accA, 0, 0, 0);     \
            accB = __builtin_amdgcn_mfma_f32_32x32x16_bf16(ahi[BASE + s8 + 1], bh1, accB, 0, 0, 0); \
            accA = __builtin_amdgcn_mfma_f32_32x32x16_bf16(alo[BASE + s8], bh0, accA, 0, 0, 0);     \
            accB = __builtin_amdgcn_mfma_f32_32x32x16_bf16(alo[BASE + s8 + 1], bh1, accB, 0, 0, 0); \
            accA = __builtin_amdgcn_mfma_f32_32x32x16_bf16(ahi[BASE + s8], bl0, accA, 0, 0, 0);     \
            accB = __builtin_amdgcn_mfma_f32_32x32x16_bf16(ahi[BASE + s8 + 1], bl1, accB, 0, 0, 0); \
        }                                                                                     \
    }

__global__ __launch_bounds__(256, 2) void dist_mfma(const float* __restrict__ zed,
                                                    const unsigned short* __restrict__ chi,
                                                    const unsigned short* __restrict__ clo,
                                                    const float* __restrict__ cnorm,
                                                    float* __restrict__ out_code,
                                                    float* __restrict__ out_loss) {
    __shared__ __align__(16) short lds_h[2][8][512];  // [buf][chunk][lane*8]
    __shared__ __align__(16) short lds_l[2][8][512];
    __shared__ float cn_s[KCODES];
    __shared__ float znorm_s[4][32];
    __shared__ float blockSum;
    const int tid = threadIdx.x;
    const int lane = tid & 63, wv = tid >> 6;
    const int cc = lane & 31, half = lane >> 5;
    const int rowBase = blockIdx.x * 128 + wv * 32;

    *(float4*)&cn_s[tid * 4] = *(const float4*)(cnorm + tid * 4);
    if (tid == 0) blockSum = 0.f;

    // A fragments: 16 chunks x (hi,lo). row = rowBase+cc, k = s*16 + half*8 + j.
    short8 ahi[16], alo[16];
    float zn = 0.f;
    const float* arow = zed + (size_t)(rowBase + cc) * DEMB + half * 8;
#pragma unroll
    for (int s = 0; s < 16; ++s) {
        const float4 v0 = *(const float4*)(arow + s * 16);
        const float4 v1 = *(const float4*)(arow + s * 16 + 4);
        const float xs[8] = {v0.x, v0.y, v0.z, v0.w, v1.x, v1.y, v1.z, v1.w};
#pragma unroll
        for (int j = 0; j < 8; ++j) {
            const unsigned short h = f2bf(xs[j]);
            ahi[s][j] = (short)h;
            alo[s][j] = (short)f2bf(xs[j] - bf2f(h));
            zn = fmaf(xs[j], xs[j], zn);
        }
    }
    zn += __shfl_xor(zn, 32, 64);  // lanes l and l^32 hold the two k-halves of row cc
    if (half == 0) znorm_s[wv][cc] = zn;

    // stage phase 0 (tile 0, chunks 0..7) into buf 0: 16 copies over 4 waves
#pragma unroll
    for (int i = 0; i < 4; ++i) {
        const int c = wv * 4 + i;
        const int s8 = c >> 1;
        const unsigned short* src = (c & 1) ? clo : chi;
        const short8 vst = *(const short8*)(src + ((size_t)s8 * 64 + lane) * 8);
        short* dst = (c & 1) ? &lds_l[0][s8][lane * 8] : &lds_h[0][s8][lane * 8];
        *(short8*)dst = vst;
    }
    __syncthreads();

    floatx16 accA, accB;
    float bestv[16];
    int besti[16];
#pragma unroll
    for (int r = 0; r < 16; ++r) {
        accA[r] = 0.f;
        accB[r] = 0.f;
        bestv[r] = INFINITY;
        besti[r] = 0;
    }
    int buf = 0;

    for (int ph = 0; ph < 64; ++ph) {
        const int t = ph >> 1;
        // T14 issue-early: load next phase's fragments into regs
        short8 pf[4];
        if (ph < 63) {
            const int tn = (ph + 1) >> 1;
            const int sb = ((ph + 1) & 1) * 8;
#pragma unroll
            for (int i = 0; i < 4; ++i) {
                const int c = wv * 4 + i;
                const int s8 = c >> 1;
                const unsigned short* src = (c & 1) ? clo : chi;
                pf[i] = *(const short8*)(src + ((size_t)(tn * 16 + sb + s8) * 64 + lane) * 8);
            }
        }
        __builtin_amdgcn_s_setprio(1);
        if ((ph & 1) == 0) {
            DIST_CHUNKS(0)
        } else {
            DIST_CHUNKS(8)
        }
        __builtin_amdgcn_s_setprio(0);
        if (ph & 1) {  // K complete for tile t: finalize 32x32 distances
            const float cn = cn_s[t * 32 + cc];
            const int code = t * 32 + cc;
#pragma unroll
            for (int r = 0; r < 16; ++r) {
                const float d = fmaf(-2.f, accA[r] + accB[r], cn);
                if (d < bestv[r]) {
                    bestv[r] = d;
                    besti[r] = code;
                }
                accA[r] = 0.f;
                accB[r] = 0.f;
            }
        }
        // T14 write-late: vmcnt drain + LDS write for next phase
        if (ph < 63) {
#pragma unroll
            for (int i = 0; i < 4; ++i) {
                const int c = wv * 4 + i;
                const int s8 = c >> 1;
                short* dst = (c & 1) ? &lds_l[buf ^ 1][s8][lane * 8]
                                     : &lds_h[buf ^ 1][s8][lane * 8];
                *(short8*)dst = pf[i];
            }
        }
        __syncthreads();
        buf ^= 1;
    }

    // reduce across the 32 lanes of each half (codes), first-index tie-break
#pragma unroll
    for (int off = 1; off < 32; off <<= 1) {
#pragma unroll
        for (int r = 0; r < 16; ++r) {
            const float ov = __shfl_xor(bestv[r], off, 64);
            const int oi = __shfl_xor(besti[r], off, 64);
            if (ov < bestv[r] || (ov == bestv[r] && oi < besti[r])) {
                bestv[r] = ov;
                besti[r] = oi;
            }
        }
    }
    if (cc == 0) {  // lanes 0 and 32 hold the 32 rows between them
        float ls = 0.f;
#pragma unroll
        for (int r = 0; r < 16; ++r) {
            const int row = (r & 3) + 8 * (r >> 2) + 4 * half;  // 32x32 C/D row map
            out_code[rowBase + row] = (float)besti[r];
            ls += bestv[r] + znorm_s[wv][row];  // ||c-z||^2
        }
        atomicAdd(&blockSum, ls);
    }
    __syncthreads();
    if (tid == 0) {
        const int b = blockIdx.x >> 5;  // 32 blocks per batch (4096/128)
        const float v = blockSum * (1.0f / (4096.0f * 256.0f));
        atomicAdd(&out_loss[b], v);
        atomicAdd(&out_loss[16 + b], v);
    }
}

// ---------------- K4: z_q[row] = P[code[row]]  (pure gather-copy) -----------
__global__ __launch_bounds__(256) void gather_kernel(const float* __restrict__ P,
                                                     const float* __restrict__ code_f,
                                                     float* __restrict__ zq) {
    const int lane = threadIdx.x & 63;
    const int row = blockIdx.x * 4 + (threadIdx.x >> 6);
    const int c = (int)code_f[row];
    const float4* src = (const float4*)(P + (size_t)c * DIN);
    float4* dst = (float4*)(zq + (size_t)row * DIN);
    dst[lane] = src[lane];
    dst[lane + 64] = src[lane + 64];
}

extern "C" void kernel_launch(void* const* d_in, const int* in_sizes, int n_in,
                              void* d_out, int out_size, void* d_ws, size_t ws_size,
                              hipStream_t stream) {
    const float* z_e = (const float*)d_in[0];      // [16,4096,512]
    const float* cbook = (const float*)d_in[1];    // [1024,256]
    const float* W_down = (const float*)d_in[2];   // [256,512]
    const float* W_up = (const float*)d_in[3];     // [512,256]

    float* out = (float*)d_out;
    float* out_zq = out;                           // 33554432
    float* out_zed = out + 33554432;               // 16777216
    float* out_code = out_zed + 16777216;          // 65536
    float* out_loss = out_code + 65536;            // 32

    // ws: [0,4K) cnorm | [4K, 4K+1.5M) swizzles | P (2 MB) overlays swizzles
    // after dist (peak 2101248 B — identical to previous footprint).
    char* wsb = (char*)d_ws;
    float* cnorm = (float*)wsb;
    unsigned short* cb_hi = (unsigned short*)(wsb + 4096);
    unsigned short* cb_lo = (unsigned short*)(wsb + 4096 + 524288);
    unsigned short* wd_hi = (unsigned short*)(wsb + 4096 + 2 * 524288);
    unsigned short* wd_lo = (unsigned short*)(wsb + 4096 + 2 * 524288 + 262144);
    float* P = (float*)(wsb + 4096);               // [1024][512]

    cnorm_kernel<<<KCODES, 256, 0, stream>>>(cbook, cnorm, out_loss);
    swz32_kernel<<<1024, 256, 0, stream>>>(cbook, cb_hi, cb_lo, 256, 262144);
    swz_kernel<<<512, 256, 0, stream>>>(W_down, wd_hi, wd_lo, 512, 131072);

    gemm_down_mfma<<<BT_TOTAL / 64, 256, 0, stream>>>(z_e, wd_hi, wd_lo, out_zed);
    dist_mfma<<<BT_TOTAL / 128, 256, 0, stream>>>(out_zed, cb_hi, cb_lo, cnorm,
                                                  out_code, out_loss);
    // P = cbook @ W_up^T (fp32 VALU; overwrites swizzle area, now dead)
    gemm_rowdot<256, 512><<<dim3(16, 8), 256, 0, stream>>>(cbook, W_up, P);
    gather_kernel<<<BT_TOTAL / 4, 256, 0, stream>>>(P, out_code, out_zq);
}